// Round 1
// baseline (21.937 us; speedup 1.0000x reference)
//
#include <hip/hip_runtime.h>
#include <hip/hip_bf16.h>

// FCOS assigner: bs=16, M=64 boxes, IMG=1024, strides {8,16,32,64,128}
// Per-batch hw = 128^2+64^2+32^2+16^2+8^2 = 21824. Total points = 349184.
// Output (float32, concatenated): cls[349184] | cnt[349184] | reg[349184*4].

#define NBOX 64
#define TOTAL_HW 21824
#define BS 16
#define BLOCK 256

__global__ __launch_bounds__(BLOCK) void fcos_assign_kernel(
    const float* __restrict__ gt_boxes,   // [bs, 64, 4] xywh
    const int*   __restrict__ gt_labels,  // [bs, 64]
    float* __restrict__ out,              // cls | cnt | reg
    int total)                            // = BS*TOTAL_HW
{
    __shared__ float sx0[NBOX], sy0[NBOX], sx1[NBOX], sy1[NBOX];
    __shared__ float scx[NBOX], scy[NBOX];
    __shared__ int   slab[NBOX];

    const int b = blockIdx.y;
    const int t = threadIdx.x;

    if (t < NBOX) {
        float4 bx = reinterpret_cast<const float4*>(gt_boxes)[b * NBOX + t];
        float x0 = bx.x, y0 = bx.y;
        float x1 = x0 + bx.z;   // xywh -> xyxy, same f32 op order as reference
        float y1 = y0 + bx.w;
        sx0[t] = x0; sy0[t] = y0; sx1[t] = x1; sy1[t] = y1;
        scx[t] = (x0 + x1) * 0.5f;
        scy[t] = (y0 + y1) * 0.5f;
        slab[t] = gt_labels[b * NBOX + t];
    }
    __syncthreads();

    const int p = blockIdx.x * BLOCK + t;
    if (p >= TOTAL_HW) return;

    // level decomposition (concat order: stride 8,16,32,64,128; x fastest)
    int q, fw;
    float stride_f, lo, hi;
    if (p < 16384)      { q = p;         fw = 128; stride_f = 8.f;   lo = -1.f;  hi = 64.f; }
    else if (p < 20480) { q = p - 16384; fw = 64;  stride_f = 16.f;  lo = 64.f;  hi = 128.f; }
    else if (p < 21504) { q = p - 20480; fw = 32;  stride_f = 32.f;  lo = 128.f; hi = 256.f; }
    else if (p < 21760) { q = p - 21504; fw = 16;  stride_f = 64.f;  lo = 256.f; hi = 512.f; }
    else                { q = p - 21760; fw = 8;   stride_f = 128.f; lo = 512.f; hi = 999999.f; }

    const float px = (float)(q % fw) * stride_f + stride_f * 0.5f;
    const float py = (float)(q / fw) * stride_f + stride_f * 0.5f;
    const float radiu = stride_f * 1.5f;

    float best = 99999999.0f;  // BIG
    float bl = 0.f, bt = 0.f, br = 0.f, bb = 0.f;
    int   blab = -1;
    bool  any = false;

    #pragma unroll 4
    for (int m = 0; m < NBOX; ++m) {
        const float l  = px - sx0[m];
        const float tt = py - sy0[m];
        const float r  = sx1[m] - px;
        const float bo = sy1[m] - py;
        const float area = (l + r) * (tt + bo);
        const float omin = fminf(fminf(l, tt), fminf(r, bo));
        const float omax = fmaxf(fmaxf(l, tt), fmaxf(r, bo));
        const float coff = fmaxf(fabsf(px - scx[m]), fabsf(py - scy[m]));
        const bool pos = (omin > 0.f) & (omax > lo) & (omax <= hi) & (coff < radiu);
        if (pos && area < best) {   // strict < -> first-occurrence argmin
            best = area;
            bl = l; bt = tt; br = r; bb = bo;
            blab = slab[m];
            any = true;
        }
    }

    const int gidx = b * TOTAL_HW + p;
    float cls, cnt;
    float4 reg;
    if (any) {
        cls = (float)blab;
        const float lrmin = fminf(bl, br), lrmax = fmaxf(bl, br);
        const float tbmin = fminf(bt, bb), tbmax = fmaxf(bt, bb);
        const float ratio = lrmin * tbmin / (lrmax * tbmax + 1e-10f);
        cnt = sqrtf(ratio);
        reg = make_float4(bl, bt, br, bb);
    } else {
        cls = -1.f;
        cnt = -1.f;
        reg = make_float4(-1.f, -1.f, -1.f, -1.f);
    }

    out[gidx] = cls;
    out[total + gidx] = cnt;
    reinterpret_cast<float4*>(out + 2 * (size_t)total)[gidx] = reg;
}

extern "C" void kernel_launch(void* const* d_in, const int* in_sizes, int n_in,
                              void* d_out, int out_size, void* d_ws, size_t ws_size,
                              hipStream_t stream) {
    const float* gt_boxes = (const float*)d_in[0];
    const int*   gt_labels = (const int*)d_in[1];
    float* out = (float*)d_out;
    const int total = BS * TOTAL_HW;  // 349184; out_size == 6*total

    dim3 grid((TOTAL_HW + BLOCK - 1) / BLOCK, BS);
    fcos_assign_kernel<<<grid, BLOCK, 0, stream>>>(gt_boxes, gt_labels, out, total);
}

// Round 2
// 16.690 us; speedup vs baseline: 1.3143x; 1.3143x over previous
//
#include <hip/hip_runtime.h>
#include <hip/hip_bf16.h>

// FCOS assigner, scatter formulation.
// bs=16, M=64 boxes, IMG=1024, strides {8,16,32,64,128}.
// Per-batch hw = 128^2+64^2+32^2+16^2+8^2 = 21824; total = 349184 points.
// Output f32 concat: cls[349184] | cnt[349184] | reg[349184*4].
//
// Insight: mask_center (c_off_max < 1.5*stride) limits each box to <=3x3
// candidate cells per level -> scatter boxes into a per-point atomicMin on a
// packed key (area_bits<<32 | box_idx). area=(l+r)*(t+b) > 0 for positive
// candidates, so uint bits are monotonic; min key == first-occurrence argmin.

#define NBOX 64
#define TOTAL_HW 21824
#define BS 16
#define BLOCK 256
#define NLVL 5

__global__ __launch_bounds__(128) void fcos_scatter(
    const float* __restrict__ gt_boxes,     // [bs,64,4] xywh
    unsigned long long* __restrict__ keys)  // [bs, TOTAL_HW]
{
    const int tid = blockIdx.x * 128 + threadIdx.x;
    if (tid >= BS * NBOX * NLVL) return;
    const int lvl = tid % NLVL;
    const int bm  = tid / NLVL;       // b*64 + m
    const int b   = bm >> 6;
    const int m   = bm & 63;

    const float4 bx = reinterpret_cast<const float4*>(gt_boxes)[bm];
    const float x0 = bx.x, y0 = bx.y;
    const float x1 = x0 + bx.z;       // same f32 op order as reference
    const float y1 = y0 + bx.w;
    const float cx = (x0 + x1) * 0.5f;
    const float cy = (y0 + y1) * 0.5f;

    const int   fw    = 128 >> lvl;
    const float s     = (float)(8 << lvl);
    const float lo    = (lvl == 0) ? -1.f : (float)(64 << (lvl - 1));
    const float hi    = (lvl == 4) ? 999999.f : (float)(64 << lvl);
    const float radiu = s * 1.5f;
    // level offset within per-batch concat: 0,16384,20480,21504,21760
    const int off = (lvl == 0) ? 0 : (lvl == 1) ? 16384 : (lvl == 2) ? 20480
                  : (lvl == 3) ? 21504 : 21760;

    // candidate window: ints in open interval (c/s - 2, c/s + 1); 4-wide
    // window with exact per-cell mask test absorbs any floor rounding.
    const int i0 = (int)floorf(cx / s - 2.0f);
    const int j0 = (int)floorf(cy / s - 2.0f);

    unsigned long long* kb = keys + (size_t)b * TOTAL_HW + off;

    #pragma unroll
    for (int dj = 0; dj < 4; ++dj) {
        const int j = j0 + dj;
        if (j < 0 || j >= fw) continue;
        const float py = (float)j * s + s * 0.5f;
        #pragma unroll
        for (int di = 0; di < 4; ++di) {
            const int i = i0 + di;
            if (i < 0 || i >= fw) continue;
            const float px = (float)i * s + s * 0.5f;

            const float l  = px - x0;
            const float tt = py - y0;
            const float r  = x1 - px;
            const float bo = y1 - py;
            const float omin = fminf(fminf(l, tt), fminf(r, bo));
            const float omax = fmaxf(fmaxf(l, tt), fmaxf(r, bo));
            const float coff = fmaxf(fabsf(px - cx), fabsf(py - cy));
            if ((omin > 0.f) & (omax > lo) & (omax <= hi) & (coff < radiu)) {
                const float area = (l + r) * (tt + bo);   // > 0 here
                const unsigned long long key =
                    ((unsigned long long)__float_as_uint(area) << 32) |
                    (unsigned long long)m;
                atomicMin(kb + j * fw + i, key);
            }
        }
    }
}

__global__ __launch_bounds__(BLOCK) void fcos_gather(
    const float* __restrict__ gt_boxes,
    const int*   __restrict__ gt_labels,
    const unsigned long long* __restrict__ keys,
    float* __restrict__ out,
    int total)
{
    const int b = blockIdx.y;
    const int p = blockIdx.x * BLOCK + threadIdx.x;
    if (p >= TOTAL_HW) return;
    const int gidx = b * TOTAL_HW + p;

    const unsigned long long key = keys[gidx];

    float cls = -1.f, cnt = -1.f;
    float4 reg = make_float4(-1.f, -1.f, -1.f, -1.f);

    if ((unsigned)(key >> 32) != 0xFFFFFFFFu) {
        // level decomposition (x fastest within each level)
        int q, fw;
        float s;
        if (p < 16384)      { q = p;         fw = 128; s = 8.f;   }
        else if (p < 20480) { q = p - 16384; fw = 64;  s = 16.f;  }
        else if (p < 21504) { q = p - 20480; fw = 32;  s = 32.f;  }
        else if (p < 21760) { q = p - 21504; fw = 16;  s = 64.f;  }
        else                { q = p - 21760; fw = 8;   s = 128.f; }
        const float px = (float)(q % fw) * s + s * 0.5f;
        const float py = (float)(q / fw) * s + s * 0.5f;

        const int m = (int)(key & 63ULL);
        const float4 bx = reinterpret_cast<const float4*>(gt_boxes)[b * NBOX + m];
        const float x0 = bx.x, y0 = bx.y;
        const float x1 = x0 + bx.z;
        const float y1 = y0 + bx.w;

        const float l  = px - x0;
        const float tt = py - y0;
        const float r  = x1 - px;
        const float bo = y1 - py;

        cls = (float)gt_labels[b * NBOX + m];
        const float lrmin = fminf(l, r),  lrmax = fmaxf(l, r);
        const float tbmin = fminf(tt, bo), tbmax = fmaxf(tt, bo);
        cnt = sqrtf(lrmin * tbmin / (lrmax * tbmax + 1e-10f));
        reg = make_float4(l, tt, r, bo);
    }

    out[gidx] = cls;
    out[total + gidx] = cnt;
    reinterpret_cast<float4*>(out + 2 * (size_t)total)[gidx] = reg;
}

extern "C" void kernel_launch(void* const* d_in, const int* in_sizes, int n_in,
                              void* d_out, int out_size, void* d_ws, size_t ws_size,
                              hipStream_t stream) {
    const float* gt_boxes  = (const float*)d_in[0];
    const int*   gt_labels = (const int*)d_in[1];
    float* out = (float*)d_out;
    const int total = BS * TOTAL_HW;                 // 349184
    unsigned long long* keys = (unsigned long long*)d_ws;
    const size_t key_bytes = (size_t)total * sizeof(unsigned long long);  // ~2.8 MB

    hipMemsetAsync(keys, 0xFF, key_bytes, stream);

    const int nscatter = BS * NBOX * NLVL;           // 5120
    fcos_scatter<<<(nscatter + 127) / 128, 128, 0, stream>>>(gt_boxes, keys);

    dim3 grid((TOTAL_HW + BLOCK - 1) / BLOCK, BS);
    fcos_gather<<<grid, BLOCK, 0, stream>>>(gt_boxes, gt_labels, keys, out, total);
}

// Round 3
// 10.250 us; speedup vs baseline: 2.1401x; 1.6283x over previous
//
#include <hip/hip_runtime.h>
#include <hip/hip_bf16.h>

// FCOS assigner, fused single-dispatch tile-scatter formulation.
// bs=16, M=64 boxes, IMG=1024, strides {8,16,32,64,128}.
// Per-batch hw = 16384+4096+1024+256+64 = 21824; total = 349184 points.
// Output f32 concat: cls[349184] | cnt[349184] | reg[349184*4].
//
// Each 256-point chunk lies within a single level (boundaries are multiples
// of 256). Per block: stage boxes in LDS -> scatter 64 boxes into a 256-slot
// LDS key array (atomicMin on (area_bits<<32)|m; area>0 so f32 bits are
// monotonic; low bits = box idx -> exact first-occurrence argmin) -> gather.

#define NBOX 64
#define TOTAL_HW 21824
#define BS 16
#define BLOCK 256
typedef unsigned long long ull;

__global__ __launch_bounds__(BLOCK) void fcos_fused(
    const float* __restrict__ gt_boxes,   // [bs,64,4] xywh
    const int*   __restrict__ gt_labels,  // [bs,64]
    float* __restrict__ out,
    int total)
{
    __shared__ float sx0[NBOX], sy0[NBOX], sx1[NBOX], sy1[NBOX];
    __shared__ float scx[NBOX], scy[NBOX];
    __shared__ int   slab[NBOX];
    __shared__ ull   lkeys[BLOCK];

    const int c = blockIdx.x;      // chunk 0..85
    const int b = blockIdx.y;
    const int t = threadIdx.x;

    // chunk -> level geometry (wave-uniform)
    int lvl, base, fw, lg2fw;
    if (c < 64)      { lvl = 0; base = 0;     fw = 128; lg2fw = 7; }
    else if (c < 80) { lvl = 1; base = 16384; fw = 64;  lg2fw = 6; }
    else if (c < 84) { lvl = 2; base = 20480; fw = 32;  lg2fw = 5; }
    else if (c == 84){ lvl = 3; base = 21504; fw = 16;  lg2fw = 4; }
    else             { lvl = 4; base = 21760; fw = 8;   lg2fw = 3; }
    const float s     = (float)(8 << lvl);
    const float lo    = (lvl == 0) ? -1.f : (float)(64 << (lvl - 1));
    const float hi    = (lvl == 4) ? 999999.f : (float)(64 << lvl);
    const float radiu = s * 1.5f;
    const int p0     = c * BLOCK;
    const int local0 = p0 - base;
    const int r0     = local0 >> lg2fw;          // first grid row of tile
    const int tileN  = (c == 85) ? 64 : BLOCK;   // lvl4 level is only 64 pts
    const int nrows  = tileN >> lg2fw;

    // init keys + stage boxes
    lkeys[t] = ~0ULL;
    if (t < NBOX) {
        float4 bx = reinterpret_cast<const float4*>(gt_boxes)[b * NBOX + t];
        float x0 = bx.x, y0 = bx.y;
        float x1 = x0 + bx.z;      // same f32 op order as reference
        float y1 = y0 + bx.w;
        sx0[t] = x0; sy0[t] = y0; sx1[t] = x1; sy1[t] = y1;
        scx[t] = (x0 + x1) * 0.5f;
        scy[t] = (y0 + y1) * 0.5f;
        slab[t] = gt_labels[b * NBOX + t];
    }
    __syncthreads();

    // scatter: thread handles box m, window-row dj; <=3 candidate cols/rows,
    // 4-wide window absorbs floor rounding; exact mask test per cell.
    {
        const int m  = t & 63;
        const int dj = t >> 6;
        const float cx = scx[m], cy = scy[m];
        const int j = (int)floorf(cy / s - 2.0f) + dj;
        if (j >= r0 && j < r0 + nrows) {
            const float py = (float)j * s + s * 0.5f;
            const float tt = py - sy0[m];
            const float bo = sy1[m] - py;
            const float ady = fabsf(py - cy);
            const int i0 = (int)floorf(cx / s - 2.0f);
            #pragma unroll
            for (int di = 0; di < 4; ++di) {
                const int i = i0 + di;
                if (i < 0 || i >= fw) continue;
                const float px = (float)i * s + s * 0.5f;
                const float l  = px - sx0[m];
                const float r  = sx1[m] - px;
                const float omin = fminf(fminf(l, tt), fminf(r, bo));
                const float omax = fmaxf(fmaxf(l, tt), fmaxf(r, bo));
                const float coff = fmaxf(fabsf(px - cx), ady);
                if ((omin > 0.f) & (omax > lo) & (omax <= hi) & (coff < radiu)) {
                    const float area = (l + r) * (tt + bo);   // > 0 here
                    const ull key = ((ull)__float_as_uint(area) << 32) | (ull)m;
                    atomicMin(&lkeys[((j - r0) << lg2fw) + i], key);
                }
            }
        }
    }
    __syncthreads();

    // gather
    if (t < tileN) {
        const ull key = lkeys[t];
        const int gidx = b * TOTAL_HW + p0 + t;

        float cls = -1.f, cnt = -1.f;
        float4 reg = make_float4(-1.f, -1.f, -1.f, -1.f);

        if ((long long)key >= 0) {   // valid: area sign bit 0; empty = ~0
            const int q = local0 + t;
            const float px = (float)(q & (fw - 1)) * s + s * 0.5f;
            const float py = (float)(q >> lg2fw) * s + s * 0.5f;
            const int m = (int)(key & 63ULL);

            const float l  = px - sx0[m];
            const float tt = py - sy0[m];
            const float r  = sx1[m] - px;
            const float bo = sy1[m] - py;

            cls = (float)slab[m];
            const float lrmin = fminf(l, r),  lrmax = fmaxf(l, r);
            const float tbmin = fminf(tt, bo), tbmax = fmaxf(tt, bo);
            cnt = sqrtf(lrmin * tbmin / (lrmax * tbmax + 1e-10f));
            reg = make_float4(l, tt, r, bo);
        }

        out[gidx] = cls;
        out[total + gidx] = cnt;
        reinterpret_cast<float4*>(out + 2 * (size_t)total)[gidx] = reg;
    }
}

extern "C" void kernel_launch(void* const* d_in, const int* in_sizes, int n_in,
                              void* d_out, int out_size, void* d_ws, size_t ws_size,
                              hipStream_t stream) {
    const float* gt_boxes  = (const float*)d_in[0];
    const int*   gt_labels = (const int*)d_in[1];
    float* out = (float*)d_out;
    const int total = BS * TOTAL_HW;   // 349184

    dim3 grid(86, BS);                 // 86 chunks of 256 pts per batch
    fcos_fused<<<grid, BLOCK, 0, stream>>>(gt_boxes, gt_labels, out, total);
}

// Round 4
// 10.239 us; speedup vs baseline: 2.1424x; 1.0011x over previous
//
#include <hip/hip_runtime.h>
#include <hip/hip_bf16.h>

// FCOS assigner, fused single-dispatch tile-scatter, 512-thread blocks
// (2 chunks of 256 points per block; 688 blocks total).
// bs=16, M=64 boxes, IMG=1024, strides {8,16,32,64,128}.
// Per-batch hw = 16384+4096+1024+256+64 = 21824; total = 349184 points.
// Output f32 concat: cls[349184] | cnt[349184] | reg[349184*4].
//
// Per block: stage boxes in LDS -> scatter 64 boxes into per-chunk 256-slot
// LDS key arrays (atomicMin on (area_bits<<32)|m; area>0 so f32 bits are
// monotonic; low bits = box idx -> exact first-occurrence argmin) -> gather.

#define NBOX 64
#define TOTAL_HW 21824
#define BS 16
typedef unsigned long long ull;

__device__ __forceinline__ void chunk_geom(int c, int& lvl, int& base,
                                           int& fw, int& lg2fw, int& tileN) {
    if (c < 64)      { lvl = 0; base = 0;     fw = 128; lg2fw = 7; tileN = 256; }
    else if (c < 80) { lvl = 1; base = 16384; fw = 64;  lg2fw = 6; tileN = 256; }
    else if (c < 84) { lvl = 2; base = 20480; fw = 32;  lg2fw = 5; tileN = 256; }
    else if (c == 84){ lvl = 3; base = 21504; fw = 16;  lg2fw = 4; tileN = 256; }
    else             { lvl = 4; base = 21760; fw = 8;   lg2fw = 3; tileN = 64;  }
}

__global__ __launch_bounds__(512) void fcos_fused(
    const float* __restrict__ gt_boxes,   // [bs,64,4] xywh
    const int*   __restrict__ gt_labels,  // [bs,64]
    float* __restrict__ out,
    int total)
{
    __shared__ float sx0[NBOX], sy0[NBOX], sx1[NBOX], sy1[NBOX];
    __shared__ float scx[NBOX], scy[NBOX];
    __shared__ int   slab[NBOX];
    __shared__ ull   lkeys[512];

    const int b = blockIdx.y;
    const int t = threadIdx.x;
    const int h  = t >> 8;                // chunk half 0/1
    const int t2 = t & 255;
    const int c  = blockIdx.x * 2 + h;    // chunk 0..85 (wave-uniform)

    int lvl, base, fw, lg2fw, tileN;
    chunk_geom(c, lvl, base, fw, lg2fw, tileN);
    const float s     = (float)(8 << lvl);
    const float lo    = (lvl == 0) ? -1.f : (float)(64 << (lvl - 1));
    const float hi    = (lvl == 4) ? 999999.f : (float)(64 << lvl);
    const float radiu = s * 1.5f;
    const int p0     = c * 256;
    const int local0 = p0 - base;
    const int r0     = local0 >> lg2fw;   // first grid row of tile
    const int nrows  = tileN >> lg2fw;

    // init keys + stage boxes
    lkeys[t] = ~0ULL;
    if (t < NBOX) {
        float4 bx = reinterpret_cast<const float4*>(gt_boxes)[b * NBOX + t];
        float x0 = bx.x, y0 = bx.y;
        float x1 = x0 + bx.z;             // same f32 op order as reference
        float y1 = y0 + bx.w;
        sx0[t] = x0; sy0[t] = y0; sx1[t] = x1; sy1[t] = y1;
        scx[t] = (x0 + x1) * 0.5f;
        scy[t] = (y0 + y1) * 0.5f;
        slab[t] = gt_labels[b * NBOX + t];
    }
    __syncthreads();

    // scatter: thread = (half, box m, window-row dj); <=3 candidate cols/rows,
    // 4-wide window absorbs floor rounding; exact mask test per cell.
    {
        const int m  = t2 & 63;
        const int dj = t2 >> 6;
        const float cx = scx[m], cy = scy[m];
        const int j = (int)floorf(cy / s - 2.0f) + dj;
        if (j >= r0 && j < r0 + nrows) {
            const float py = (float)j * s + s * 0.5f;
            const float tt = py - sy0[m];
            const float bo = sy1[m] - py;
            const float ady = fabsf(py - cy);
            const int i0 = (int)floorf(cx / s - 2.0f);
            #pragma unroll
            for (int di = 0; di < 4; ++di) {
                const int i = i0 + di;
                if (i < 0 || i >= fw) continue;
                const float px = (float)i * s + s * 0.5f;
                const float l  = px - sx0[m];
                const float r  = sx1[m] - px;
                const float omin = fminf(fminf(l, tt), fminf(r, bo));
                const float omax = fmaxf(fmaxf(l, tt), fmaxf(r, bo));
                const float coff = fmaxf(fabsf(px - cx), ady);
                if ((omin > 0.f) & (omax > lo) & (omax <= hi) & (coff < radiu)) {
                    const float area = (l + r) * (tt + bo);   // > 0 here
                    const ull key = ((ull)__float_as_uint(area) << 32) | (ull)m;
                    atomicMin(&lkeys[(h << 8) + ((j - r0) << lg2fw) + i], key);
                }
            }
        }
    }
    __syncthreads();

    // gather
    if (t2 < tileN) {
        const ull key = lkeys[t];
        const int gidx = b * TOTAL_HW + p0 + t2;

        float cls = -1.f, cnt = -1.f;
        float4 reg = make_float4(-1.f, -1.f, -1.f, -1.f);

        if ((long long)key >= 0) {   // valid: area sign bit 0; empty = ~0
            const int q = local0 + t2;
            const float px = (float)(q & (fw - 1)) * s + s * 0.5f;
            const float py = (float)(q >> lg2fw) * s + s * 0.5f;
            const int m = (int)(key & 63ULL);

            const float l  = px - sx0[m];
            const float tt = py - sy0[m];
            const float r  = sx1[m] - px;
            const float bo = sy1[m] - py;

            cls = (float)slab[m];
            const float lrmin = fminf(l, r),  lrmax = fmaxf(l, r);
            const float tbmin = fminf(tt, bo), tbmax = fmaxf(tt, bo);
            cnt = sqrtf(lrmin * tbmin / (lrmax * tbmax + 1e-10f));
            reg = make_float4(l, tt, r, bo);
        }

        out[gidx] = cls;
        out[total + gidx] = cnt;
        reinterpret_cast<float4*>(out + 2 * (size_t)total)[gidx] = reg;
    }
}

extern "C" void kernel_launch(void* const* d_in, const int* in_sizes, int n_in,
                              void* d_out, int out_size, void* d_ws, size_t ws_size,
                              hipStream_t stream) {
    const float* gt_boxes  = (const float*)d_in[0];
    const int*   gt_labels = (const int*)d_in[1];
    float* out = (float*)d_out;
    const int total = BS * TOTAL_HW;   // 349184

    dim3 grid(43, BS);                 // 43 chunk-pairs x 16 batches
    fcos_fused<<<grid, 512, 0, stream>>>(gt_boxes, gt_labels, out, total);
}